// Round 7
// baseline (177.714 us; speedup 1.0000x reference)
//
#include <hip/hip_runtime.h>
#include <hip/hip_bf16.h>

#define Bn 4
#define Nn 2048
#define Fn 128
#define Hn 4
#define Dn 32
#define LOG2E 1.44269504f

typedef __attribute__((ext_vector_type(4))) float f32x4;
typedef __attribute__((ext_vector_type(4))) int   i32x4;
typedef __attribute__((ext_vector_type(8))) short s16x8;
typedef __attribute__((ext_vector_type(4))) short s16x4;
typedef _Float16 f16x8 __attribute__((ext_vector_type(8)));

typedef unsigned int uint;

__device__ __forceinline__ unsigned short f2h(float f) {
  _Float16 h = (_Float16)f;
  return __builtin_bit_cast(unsigned short, h);
}

// ---------------------------------------------------------------------------
// k_pack: adj (2048x2048 fp32 0/1) -> bit mask (bit n&63 of u64 n>>6, per row).
// W (H,F,D fp32) -> Wt[c][k] fp16 (c=h*32+d, pitch Fn) AND
// Waux[cc][k] fp16 (cc = h*2+{L,R}, rows 8..15 zero), Waux = (W@a)*log2e.
// ---------------------------------------------------------------------------
__global__ __launch_bounds__(256) void k_pack(
    const float* __restrict__ adj, const float* __restrict__ W,
    const float* __restrict__ aL, const float* __restrict__ aR,
    unsigned long long* __restrict__ adjbits, short* __restrict__ Wt,
    short* __restrict__ Waux)
{
  const int blk = blockIdx.x;
  const int t = threadIdx.x;
  if (blk < Nn) {                       // adj row blk
    const int wv = t >> 6, lane = t & 63;
    const float* ap = adj + (size_t)blk * Nn;
    #pragma unroll
    for (int s = 0; s < 8; ++s) {
      const int n0 = (wv * 8 + s) * 64;
      const unsigned long long m = __ballot(ap[n0 + lane] > 0.5f);
      if (lane == 0) adjbits[blk * 32 + wv * 8 + s] = m;
    }
  } else if (t < 128) {                 // W pack, one block per head
    const int h = blk - Nn;
    const int f = t;
    const float* Wp = W + ((size_t)h * Fn + f) * Dn;   // W[h][f][0..31]
    float wv[32];
    float dl = 0.f, dr = 0.f;
    #pragma unroll
    for (int d4 = 0; d4 < 8; ++d4) {
      const f32x4 w4 = *(const f32x4*)(Wp + d4 * 4);
      #pragma unroll
      for (int j = 0; j < 4; ++j) {
        const int d = d4 * 4 + j;
        wv[d] = w4[j];
        dl = fmaf(w4[j], aL[h * Dn + d], dl);
        dr = fmaf(w4[j], aR[h * Dn + d], dr);
      }
    }
    #pragma unroll
    for (int d = 0; d < 32; ++d)
      Wt[(h * Dn + d) * Fn + f] = (short)f2h(wv[d]);
    Waux[(h * 2 + 0) * Fn + f] = (short)f2h(dl * LOG2E);
    Waux[(h * 2 + 1) * Fn + f] = (short)f2h(dr * LOG2E);
    if (h == 0) {
      #pragma unroll
      for (int cc = 8; cc < 16; ++cc) Waux[cc * Fn + f] = 0;
    }
  }
}

// ---------------------------------------------------------------------------
// k_proj: h = x@W via mfma_f32_16x16x32_f16, one wave / 16 rows; aux MFMA
// gives al/ar (log2-domain). Epilogue converts to the SEPARABLE exp factors:
//   EA = 2^(al-2), FA = 2^(0.2*al-2)  -> packed u32 eafa[bh][n]
//   ER = 2^(ar-2), FR = 2^(0.2*ar-2)  -> fp16 arrays erh/frh[bh][n]
// so k_attn computes p = max(EA*ER, FA*FR) with NO exp at all.
// ht = fp16 h stored transposed [bh][d][n].
// ---------------------------------------------------------------------------
__global__ __launch_bounds__(64, 4) void k_proj(
    const float* __restrict__ x, const short* __restrict__ Wt,
    const short* __restrict__ Waux,
    uint* __restrict__ eafa, short* __restrict__ erh, short* __restrict__ frh,
    short* __restrict__ ht)
{
  const int m0 = blockIdx.x * 16;          // flattened row base (B*N = 8192)
  const int b = m0 >> 11, nloc = m0 & 2047;
  const int lane = threadIdx.x;
  const int r = lane & 15, g = lane >> 4;

  const float* xp = x + (size_t)(m0 + r) * Fn + g * 8;
  f32x4 c[8] = {};
  f32x4 caux = {};
  #pragma unroll
  for (int ks = 0; ks < 4; ++ks) {
    const f32x4 xa = *(const f32x4*)(xp + ks * 32);
    const f32x4 xb = *(const f32x4*)(xp + ks * 32 + 4);
    f16x8 af;
    #pragma unroll
    for (int j = 0; j < 4; ++j) { af[j] = (_Float16)xa[j]; af[j + 4] = (_Float16)xb[j]; }
    const short* wp = Wt + r * Fn + ks * 32 + g * 8;     // col = cf*16 + r
    #pragma unroll
    for (int cf = 0; cf < 8; ++cf) {
      const f16x8 bf = __builtin_bit_cast(f16x8, *(const s16x8*)(wp + cf * 16 * Fn));
      c[cf] = __builtin_amdgcn_mfma_f32_16x16x32_f16(af, bf, c[cf], 0, 0, 0);
    }
    const f16x8 ba = __builtin_bit_cast(f16x8, *(const s16x8*)(Waux + r * Fn + ks * 32 + g * 8));
    caux = __builtin_amdgcn_mfma_f32_16x16x32_f16(af, ba, caux, 0, 0, 0);
  }

  // ht store: frag cf -> head cf>>1, d = (cf&1)*16 + r, rows nloc + g*4 + q
  #pragma unroll
  for (int cf = 0; cf < 8; ++cf) {
    const int hd = cf >> 1, d = (cf & 1) * 16 + r;
    s16x4 hv;
    #pragma unroll
    for (int q = 0; q < 4; ++q) hv[q] = (short)f2h(c[cf][q]);
    *(s16x4*)(ht + ((size_t)(b * Hn + hd) * Dn + d) * Nn + nloc + g * 4) = hv;
  }

  // caux[q] = aux[row = g*4+q][cc = r], cc = head*2 + {0=L,1=R}
  if (r < 8) {
    const int hh = r >> 1, side = r & 1;
    #pragma unroll
    for (int q = 0; q < 4; ++q) {
      const float v = caux[q];                         // al/ar * log2e
      const float Ev = __builtin_amdgcn_exp2f(v - 2.0f);
      const float Fv = __builtin_amdgcn_exp2f(fmaf(0.2f, v, -2.0f));
      const size_t idx = (size_t)(b * Hn + hh) * Nn + nloc + g * 4 + q;
      if (side == 0) {
        eafa[idx] = (uint)f2h(Ev) | ((uint)f2h(Fv) << 16);
      } else {
        erh[idx] = (short)f2h(Ev);
        frh[idx] = (short)f2h(Fv);
      }
    }
  }
}

// ---------------------------------------------------------------------------
// k_attn: fused masked softmax + PV. 8 waves/block on the same 16 m-rows,
// 8-way n-split (256 n/wave, 8 chunks of 32). Inner loop: p = max(EA*ER,FA*FR)
// in packed fp16 (4 pk_mul + 4 pk_mul + 4 pk_max), bit-mask via sext-derived
// pair masks, 3 MFMAs (PV-lo, PV-hi, ones row-sum). All operand streams
// loaded via inline-asm global_load_dwordx4 with counted vmcnt(4) waits,
// 2 chunks deep (T4 pattern; sched_barrier(0) after each wait per rule #18).
// ---------------------------------------------------------------------------
__global__ __launch_bounds__(512, 4) void k_attn(
    const unsigned long long* __restrict__ adjbits,
    const uint* __restrict__ eafa,
    const short* __restrict__ erh, const short* __restrict__ frh,
    const short* __restrict__ ht, const float* __restrict__ bias,
    float* __restrict__ out)
{
  __shared__ float accS[8][16][33];
  __shared__ float lS[8][16];

  const int blk = blockIdx.x;              // 2048 = 16 bh * 128 m-tiles
  const int mt = blk & 127, bh = blk >> 7;
  const int b = bh >> 2, head = bh & 3;
  const int m0 = mt * 16;
  const int t = threadIdx.x;
  const int wv = t >> 6, lane = t & 63;
  const int r = lane & 15, g = lane >> 4;
  const int nb = wv * 256 + g * 64;        // this lane's 64-n range

  // ---- prologue (normal compiler loads, drained before the asm region) ----
  const unsigned long long abits = adjbits[(size_t)(m0 + r) * 32 + wv * 4 + g];
  const uint ef = eafa[(size_t)bh * Nn + m0 + r];
  uint ea2 = ef & 0xFFFFu;  ea2 |= ea2 << 16;
  uint fa2 = ef >> 16;      fa2 |= fa2 << 16;
  const i32x4 ea4 = {(int)ea2, (int)ea2, (int)ea2, (int)ea2};
  const i32x4 fa4 = {(int)fa2, (int)fa2, (int)fa2, (int)fa2};
  const f16x8 EA8 = __builtin_bit_cast(f16x8, ea4);
  const f16x8 FA8 = __builtin_bit_cast(f16x8, fa4);
  const f16x8 ones = {(_Float16)1.f, (_Float16)1.f, (_Float16)1.f, (_Float16)1.f,
                      (_Float16)1.f, (_Float16)1.f, (_Float16)1.f, (_Float16)1.f};

  const unsigned long long er_p = (unsigned long long)(erh + (size_t)bh * Nn + nb);
  const unsigned long long fr_p = (unsigned long long)(frh + (size_t)bh * Nn + nb);
  const unsigned long long ha_p = (unsigned long long)(ht + ((size_t)bh * Dn + r) * Nn + nb);
  const unsigned long long hb_p = ha_p + (size_t)(16 * Nn) * 2;

  f32x4 accA = {0.f,0.f,0.f,0.f}, accB = {0.f,0.f,0.f,0.f}, accL = {0.f,0.f,0.f,0.f};

  // force prologue loads complete, then drain vmcnt so counted waits are exact
  asm volatile("" :: "v"(ea4), "v"(fa4), "v"(abits));
  asm volatile("s_waitcnt vmcnt(0)");
  __builtin_amdgcn_sched_barrier(0);

  i32x4 b0_er, b0_fr, b0_ha, b0_hb;
  i32x4 b1_er, b1_fr, b1_ha, b1_hb;

  #define GLD(dst, base, OFF) \
    asm volatile("global_load_dwordx4 %0, %1, off offset:" OFF \
                 : "=v"(dst) : "v"(base))
  #define ISSUE(BUF, OFF) \
    GLD(BUF##_er, er_p, OFF); GLD(BUF##_fr, fr_p, OFF); \
    GLD(BUF##_ha, ha_p, OFF); GLD(BUF##_hb, hb_p, OFF);
  #define VWAIT(N) \
    asm volatile("s_waitcnt vmcnt(" #N ")"); __builtin_amdgcn_sched_barrier(0)

  // sext pair-mask: bits (2j,2j+1) of bb -> {lo16, hi16} all-ones/zeros
  #define PM(bb, j) (((uint)(((int)((bb) << (31 - 2*(j)))) >> 31) & 0xFFFFu) | \
                     ((uint)(((int)((bb) << (30 - 2*(j)))) >> 31) << 16))

  #define COMPUTE(ci, BUF) { \
    const f16x8 E = __builtin_bit_cast(f16x8, BUF##_er) * EA8; \
    const f16x8 F = __builtin_bit_cast(f16x8, BUF##_fr) * FA8; \
    f16x8 P = __builtin_elementwise_max(E, F); \
    i32x4 pu = __builtin_bit_cast(i32x4, P); \
    const uint bb = (uint)(abits >> (8 * ci)) & 0xffu; \
    pu[0] &= (int)PM(bb, 0); pu[1] &= (int)PM(bb, 1); \
    pu[2] &= (int)PM(bb, 2); pu[3] &= (int)PM(bb, 3); \
    P = __builtin_bit_cast(f16x8, pu); \
    accA = __builtin_amdgcn_mfma_f32_16x16x32_f16(P, __builtin_bit_cast(f16x8, BUF##_ha), accA, 0, 0, 0); \
    accB = __builtin_amdgcn_mfma_f32_16x16x32_f16(P, __builtin_bit_cast(f16x8, BUF##_hb), accB, 0, 0, 0); \
    accL = __builtin_amdgcn_mfma_f32_16x16x32_f16(P, ones, accL, 0, 0, 0); \
  }

  ISSUE(b0, "0");  ISSUE(b1, "16");
  VWAIT(4); COMPUTE(0, b0); ISSUE(b0, "32");
  VWAIT(4); COMPUTE(1, b1); ISSUE(b1, "48");
  VWAIT(4); COMPUTE(2, b0); ISSUE(b0, "64");
  VWAIT(4); COMPUTE(3, b1); ISSUE(b1, "80");
  VWAIT(4); COMPUTE(4, b0); ISSUE(b0, "96");
  VWAIT(4); COMPUTE(5, b1); ISSUE(b1, "112");
  VWAIT(4); COMPUTE(6, b0);
  VWAIT(0); COMPUTE(7, b1);
  __builtin_amdgcn_sched_barrier(0);

  #undef GLD
  #undef ISSUE
  #undef VWAIT
  #undef PM
  #undef COMPUTE

  // merge 8 n-split partials. accL[q] = row-sum of P for row 4g+q.
  #pragma unroll
  for (int q = 0; q < 4; ++q) {
    accS[wv][4 * g + q][r]      = accA[q];
    accS[wv][4 * g + q][r + 16] = accB[q];
  }
  if (r == 0) {
    #pragma unroll
    for (int q = 0; q < 4; ++q) lS[wv][4 * g + q] = accL[q];
  }
  __syncthreads();

  // epilogue: 512 threads <-> 16 rows x 32 cols
  const int row = t >> 5, dc = t & 31;
  float L = 0.f, v = 0.f;
  #pragma unroll
  for (int w = 0; w < 8; ++w) { L += lS[w][row]; v += accS[w][row][dc]; }
  v = v / L + bias[head * Dn + dc];
  v = v > 0.f ? v : __expf(v) - 1.f;       // ELU(alpha=1)
  out[((size_t)b * Nn + m0 + row) * (Hn * Dn) + head * Dn + dc] = v;
}

extern "C" void kernel_launch(void* const* d_in, const int* in_sizes, int n_in,
                              void* d_out, int out_size, void* d_ws, size_t ws_size,
                              hipStream_t stream) {
  const float* x    = (const float*)d_in[0];
  const float* adj  = (const float*)d_in[1];
  const float* W    = (const float*)d_in[2];
  const float* aL   = (const float*)d_in[3];
  const float* aR   = (const float*)d_in[4];
  const float* bias = (const float*)d_in[5];
  float* out = (float*)d_out;

  // ws layout (~2.8 MB): eafa | erh | frh | ht | adjbits | Wt | Waux
  uint*  eafa = (uint*)d_ws;                                   // 128 KB
  short* erh  = (short*)(eafa + (Bn * Hn) * Nn);               // 64 KB
  short* frh  = erh + (Bn * Hn) * Nn;                          // 64 KB
  short* ht   = frh + (Bn * Hn) * Nn;                          // 2 MB
  unsigned long long* adjbits =
      (unsigned long long*)(ht + (size_t)(Bn * Hn) * Dn * Nn); // 512 KB
  short* Wt   = (short*)(adjbits + Nn * (Nn / 64));            // 32 KB
  short* Waux = Wt + (Hn * Dn) * Fn;                           // 4 KB

  hipLaunchKernelGGL(k_pack, dim3(Nn + Hn), dim3(256), 0, stream,
                     adj, W, aL, aR, adjbits, Wt, Waux);
  hipLaunchKernelGGL(k_proj, dim3((Bn * Nn) / 16), dim3(64), 0, stream,
                     x, Wt, Waux, eafa, erh, frh, ht);
  hipLaunchKernelGGL(k_attn, dim3((Bn * Hn) * (Nn / 16)), dim3(512), 0, stream,
                     adjbits, eafa, erh, frh, ht, bias, out);
}